// Round 12
// baseline (146.640 us; speedup 1.0000x reference)
//
#include <hip/hip_runtime.h>
#include <math.h>

#define NEG_SLOPE 0.2f
typedef unsigned int uint;
typedef __attribute__((ext_vector_type(8))) short short8;
typedef __attribute__((ext_vector_type(4))) float floatx4;

__device__ __forceinline__ float lrelu(float x){ return x > 0.f ? x : NEG_SLOPE*x; }
__device__ __forceinline__ float sel4(float a,float b,float c,float d,int comp){
    return comp==0 ? a : (comp==1 ? b : (comp==2 ? c : d));
}
__device__ __forceinline__ uint f2bf(float f){
    uint u = __float_as_uint(f);
    return (u + 0x7FFFu + ((u>>16)&1u)) >> 16;
}
__device__ __forceinline__ float bf_lo(uint u){ return __uint_as_float(u<<16); }
__device__ __forceinline__ float bf_hi(uint u){ return __uint_as_float(u & 0xFFFF0000u); }
__device__ __forceinline__ float cexp(float x){ return __expf(fminf(x, 60.f)); }

// ---------------- prep: W1^T -> bf16 (16 blocks) + offs[N]=Etot ----------------
__global__ __launch_bounds__(256) void k_prep(const float* __restrict__ W,
                                              ushort* __restrict__ wtb,
                                              int* __restrict__ offs, int N, int Etot)
{
    if (blockIdx.x == 0 && threadIdx.x == 0) offs[N] = Etot;
    int flat = blockIdx.x*1024 + threadIdx.x*4;
    int k = flat >> 7, c = flat & 127;
    float4 wv = *(const float4*)&W[flat];
    wtb[(size_t)(c+0)*128 + k] = (ushort)f2bf(wv.x);
    wtb[(size_t)(c+1)*128 + k] = (ushort)f2bf(wv.y);
    wtb[(size_t)(c+2)*128 + k] = (ushort)f2bf(wv.z);
    wtb[(size_t)(c+3)*128 + k] = (ushort)f2bf(wv.w);
}

// ---------------- MERGED: MFMA GEMM1 (blocks < GB, 8 waves) + bucket histogram ----------------
__global__ __launch_bounds__(512) void k_g1b(const float* __restrict__ x,
    const ushort* __restrict__ wtb, uint* __restrict__ hb2, int N, int GB,
    const int* __restrict__ ei, int* __restrict__ bh, int E, int Etot, int NC, int NB)
{
    if (blockIdx.x >= GB){
        __shared__ uint hist[256];
        int c = blockIdx.x - GB;
        if (threadIdx.x < 256) hist[threadIdx.x] = 0;
        __syncthreads();
        int e0 = c*4096;
        #pragma unroll
        for (int r=0;r<8;r++){
            int e = e0 + r*512 + threadIdx.x;
            if (e < Etot){
                int d = (e < E) ? ei[E+e] : (e-E);
                atomicAdd(&hist[d>>8], 1u);
            }
        }
        __syncthreads();
        int b = threadIdx.x;
        if (b < NB) bh[(size_t)b*NC + c] = (int)hist[b];
        return;
    }
    __shared__ __align__(16) ushort xt[64][136];
    const int tid = threadIdx.x;
    const int row0 = blockIdx.x * 64;
    #pragma unroll
    for (int j=0;j<4;j++){
        int flat = j*2048 + tid*4;
        int r = flat >> 7, c = flat & 127;
        int gr = row0 + r;
        float4 xv = (gr < N) ? *(const float4*)&x[(size_t)gr*128 + c]
                             : make_float4(0.f,0.f,0.f,0.f);
        uint2 p;
        p.x = f2bf(xv.x) | (f2bf(xv.y)<<16);
        p.y = f2bf(xv.z) | (f2bf(xv.w)<<16);
        *(uint2*)&xt[r][c] = p;
    }
    __syncthreads();
    const int wv_ = tid >> 6, lane = tid & 63;
    const int l15 = lane & 15, hi = lane >> 4;
    const int rw = wv_ & 3, ch = wv_ >> 2;
    const int arow = rw*16 + l15;
    floatx4 acc[4];
    #pragma unroll
    for (int t=0;t<4;t++) acc[t] = (floatx4){0.f,0.f,0.f,0.f};
    #pragma unroll
    for (int ks=0; ks<4; ks++){
        short8 a = *(short8*)&xt[arow][ks*32 + hi*8];
        #pragma unroll
        for (int c4=0; c4<4; c4++){
            int ct = ch*4 + c4;
            short8 b = *(const short8*)&wtb[(size_t)(ct*16 + l15)*128 + ks*32 + hi*8];
            acc[c4] = __builtin_amdgcn_mfma_f32_16x16x32_bf16(a, b, acc[c4], 0, 0, 0);
        }
    }
    #pragma unroll
    for (int c4=0; c4<4; c4++){
        int ct = ch*4 + c4;
        #pragma unroll
        for (int r=0;r<4;r++){
            float v  = acc[c4][r];
            float pr = __shfl_xor(v, 1);
            int gr = row0 + rw*16 + (hi<<2) + r;
            if (((lane & 1) == 0) && gr < N)
                hb2[(size_t)gr*64 + ct*8 + (l15>>1)] = f2bf(v) | (f2bf(pr)<<16);
        }
    }
}

// ---------------- MERGED: alpha1 (blocks < AB) + bucket-scan level1 ----------------
__global__ __launch_bounds__(256) void k_a1sc(const uint* __restrict__ hb2,
        const float* __restrict__ at_s, const float* __restrict__ at_d,
        float* __restrict__ as1, float* __restrict__ ad1, int N, int AB,
        const int* __restrict__ bh, int* __restrict__ bhs, int* __restrict__ partials2, int T)
{
    __shared__ int sm[256];
    if (blockIdx.x >= AB){
        int bid = blockIdx.x - AB;
        int tid = threadIdx.x;
        int i = bid*256 + tid;
        int v = (i < T) ? bh[i] : 0;
        sm[tid] = v;
        __syncthreads();
        for (int d=1; d<256; d<<=1){
            int t = (tid >= d) ? sm[tid-d] : 0;
            __syncthreads();
            sm[tid] += t;
            __syncthreads();
        }
        if (i < T) bhs[i] = sm[tid] - v;
        if (tid == 255) partials2[bid] = sm[255];
        return;
    }
    int wid = (blockIdx.x << 2) + (threadIdx.x >> 6);
    int lane = threadIdx.x & 63;
    if (wid >= N) return;
    uint hv = hb2[(size_t)wid*64 + lane];
    float f0 = bf_lo(hv), f1 = bf_hi(hv);
    float2 asv = *(const float2*)&at_s[2*lane];
    float2 adv = *(const float2*)&at_d[2*lane];
    float sa = f0*asv.x + f1*asv.y;
    float da = f0*adv.x + f1*adv.y;
    #pragma unroll
    for (int d=8; d>=1; d>>=1){ sa += __shfl_xor(sa,d); da += __shfl_xor(da,d); }
    if ((lane & 15) == 0){
        int head = lane >> 4;
        as1[(size_t)wid*4 + head] = sa;
        ad1[(size_t)wid*4 + head] = da;
    }
}

// serial level-2 fallback (only if L1 > 256; produces FINAL bhs)
__global__ void k_bscan2s(int* __restrict__ bhs, const int* __restrict__ bh, int T){
    if (threadIdx.x == 0){
        int run = 0;
        for (int i=0;i<T;i++){ bhs[i] = run; run += bh[i]; }
    }
}

// ---------------- scatter edges to bucket-major order (inline level-2 scan) ----------------
__global__ __launch_bounds__(256) void k_bscat(const int* __restrict__ ei,
        const int* __restrict__ bhs, const int* __restrict__ partials2, int L1e,
        uint* __restrict__ epack, int E, int Etot, int NC, int NB)
{
    __shared__ int sm[256];
    __shared__ int pbase[256];
    __shared__ uint cnt[256];
    int c = blockIdx.x, tid = threadIdx.x;
    int v = (tid < L1e) ? partials2[tid] : 0;
    sm[tid] = v;
    __syncthreads();
    for (int d=1; d<256; d<<=1){
        int t = (tid >= d) ? sm[tid-d] : 0;
        __syncthreads();
        sm[tid] += t;
        __syncthreads();
    }
    if (tid < NB){
        int i = tid*NC + c;
        int boff = (L1e == 0 || (i>>8) == 0) ? 0 : sm[(i>>8)-1];
        pbase[tid] = bhs[i] + boff;
    }
    cnt[tid] = 0;
    __syncthreads();
    int e0 = c*4096;
    #pragma unroll
    for (int r=0;r<16;r++){
        int e = e0 + r*256 + tid;
        if (e < Etot){
            int d, s;
            if (e < E){ s = ei[e]; d = ei[E+e]; }
            else      { s = e - E; d = e - E; }
            int b = d >> 8;
            uint lr = atomicAdd(&cnt[b], 1u);
            epack[pbase[b] + (int)lr] = (uint)s | ((uint)(d & 255) << 16);
        }
    }
}

// ---------------- finalize: per-bucket node offsets + bsrc (inline level-2 scan) ----------------
__global__ __launch_bounds__(256) void k_bfin(const uint* __restrict__ epack,
        const int* __restrict__ bhs, const int* __restrict__ partials2, int L1e,
        int* __restrict__ bsrc, int* __restrict__ offs, int N, int NB, int NC, int Etot)
{
    __shared__ int sm[256];
    __shared__ int cnt[256], lofs[256], cnt2[256];
    int b = blockIdx.x, tid = threadIdx.x;
    int v = (tid < L1e) ? partials2[tid] : 0;
    sm[tid] = v;
    __syncthreads();
    for (int d=1; d<256; d<<=1){
        int t = (tid >= d) ? sm[tid-d] : 0;
        __syncthreads();
        sm[tid] += t;
        __syncthreads();
    }
    int i0 = b*NC;
    int start = bhs[i0] + ((L1e==0 || (i0>>8)==0) ? 0 : sm[(i0>>8)-1]);
    int end;
    if (b+1 < NB){
        int i1 = (b+1)*NC;
        end = bhs[i1] + ((L1e==0 || (i1>>8)==0) ? 0 : sm[(i1>>8)-1]);
    } else end = Etot;
    __syncthreads();
    cnt[tid] = 0; cnt2[tid] = 0;
    __syncthreads();
    for (int e = start + tid; e < end; e += 256)
        atomicAdd((uint*)&cnt[(epack[e] >> 16) & 255], 1u);
    __syncthreads();
    int v2 = cnt[tid];
    sm[tid] = v2;
    __syncthreads();
    for (int d=1; d<256; d<<=1){
        int t = (tid >= d) ? sm[tid-d] : 0;
        __syncthreads();
        sm[tid] += t;
        __syncthreads();
    }
    lofs[tid] = sm[tid] - v2;
    int nd = b*256 + tid;
    if (nd <= N) offs[nd] = start + sm[tid] - v2;
    __syncthreads();
    for (int e = start + tid; e < end; e += 256){
        uint u = epack[e];
        int dl = (u >> 16) & 255;
        int r = (int)atomicAdd((uint*)&cnt2[dl], 1u);
        bsrc[start + lofs[dl] + r] = (int)(u & 0xFFFFu);
    }
}

// ---------------- layer-1 softmax (max-free) + aggregate + bias + ELU -> bf16 h1 ----------------
__global__ __launch_bounds__(512) void k_agg1(const uint* __restrict__ hb2,
    const float4* __restrict__ as1v, const float4* __restrict__ ad1v,
    const int* __restrict__ offs, const int* __restrict__ bsrc,
    const float* __restrict__ b1, float* __restrict__ exb,
    uint* __restrict__ hb1, int N)
{
    __shared__ float wsh[8][64][4];   // [wave][edge][head]
    __shared__ int   ssh[8][64];      // [wave][edge] src<<6
    int wv   = threadIdx.x >> 6;
    int wid  = (blockIdx.x << 3) + wv;
    int lane = threadIdx.x & 63;
    if (wid >= N) return;
    int base = offs[wid];
    int deg  = offs[wid+1] - base;
    float4 adv = ad1v[wid];
    const int comp = lane >> 4;
    float acc0=0.f, acc1=0.f;

    if (deg <= 64){
        const bool act = lane < deg;
        int sreg = 0;
        float e0=0.f,e1=0.f,e2=0.f,e3=0.f;
        if (act){
            sreg = bsrc[base+lane];
            float4 av = as1v[sreg];
            e0=cexp(lrelu(av.x+adv.x)); e1=cexp(lrelu(av.y+adv.y));
            e2=cexp(lrelu(av.z+adv.z)); e3=cexp(lrelu(av.w+adv.w));
        }
        float s0=e0,s1=e1,s2=e2,s3=e3;
        #pragma unroll
        for (int d=32; d>=1; d>>=1){
            s0+=__shfl_xor(s0,d); s1+=__shfl_xor(s1,d);
            s2+=__shfl_xor(s2,d); s3+=__shfl_xor(s3,d);
        }
        if (act){
            float i0=__builtin_amdgcn_rcpf(s0), i1=__builtin_amdgcn_rcpf(s1);
            float i2=__builtin_amdgcn_rcpf(s2), i3=__builtin_amdgcn_rcpf(s3);
            ssh[wv][lane]    = sreg << 6;
            wsh[wv][lane][0] = e0*i0;
            wsh[wv][lane][1] = e1*i1;
            wsh[wv][lane][2] = e2*i2;
            wsh[wv][lane][3] = e3*i3;
        }
        int j=0;
        for (; j+7 < deg; j+=8){
            uint o0=ssh[wv][j+0]+lane, o1=ssh[wv][j+1]+lane;
            uint o2=ssh[wv][j+2]+lane, o3=ssh[wv][j+3]+lane;
            uint o4=ssh[wv][j+4]+lane, o5=ssh[wv][j+5]+lane;
            uint o6=ssh[wv][j+6]+lane, o7=ssh[wv][j+7]+lane;
            float w0=wsh[wv][j+0][comp], w1=wsh[wv][j+1][comp];
            float w2=wsh[wv][j+2][comp], w3=wsh[wv][j+3][comp];
            float w4=wsh[wv][j+4][comp], w5=wsh[wv][j+5][comp];
            float w6=wsh[wv][j+6][comp], w7=wsh[wv][j+7][comp];
            uint h0=hb2[o0], h1_=hb2[o1], h2_=hb2[o2], h3=hb2[o3];
            uint h4=hb2[o4], h5=hb2[o5], h6=hb2[o6], h7=hb2[o7];
            acc0 = fmaf(bf_lo(h0), w0, acc0); acc1 = fmaf(bf_hi(h0), w0, acc1);
            acc0 = fmaf(bf_lo(h1_),w1, acc0); acc1 = fmaf(bf_hi(h1_),w1, acc1);
            acc0 = fmaf(bf_lo(h2_),w2, acc0); acc1 = fmaf(bf_hi(h2_),w2, acc1);
            acc0 = fmaf(bf_lo(h3), w3, acc0); acc1 = fmaf(bf_hi(h3), w3, acc1);
            acc0 = fmaf(bf_lo(h4), w4, acc0); acc1 = fmaf(bf_hi(h4), w4, acc1);
            acc0 = fmaf(bf_lo(h5), w5, acc0); acc1 = fmaf(bf_hi(h5), w5, acc1);
            acc0 = fmaf(bf_lo(h6), w6, acc0); acc1 = fmaf(bf_hi(h6), w6, acc1);
            acc0 = fmaf(bf_lo(h7), w7, acc0); acc1 = fmaf(bf_hi(h7), w7, acc1);
        }
        for (; j+3 < deg; j+=4){
            uint oA=ssh[wv][j]+lane,   oB=ssh[wv][j+1]+lane;
            uint oC=ssh[wv][j+2]+lane, oD=ssh[wv][j+3]+lane;
            float wA=wsh[wv][j][comp],   wB=wsh[wv][j+1][comp];
            float wC=wsh[wv][j+2][comp], wD=wsh[wv][j+3][comp];
            uint hA=hb2[oA], hB=hb2[oB], hC=hb2[oC], hD=hb2[oD];
            acc0 = fmaf(bf_lo(hA), wA, acc0); acc1 = fmaf(bf_hi(hA), wA, acc1);
            acc0 = fmaf(bf_lo(hB), wB, acc0); acc1 = fmaf(bf_hi(hB), wB, acc1);
            acc0 = fmaf(bf_lo(hC), wC, acc0); acc1 = fmaf(bf_hi(hC), wC, acc1);
            acc0 = fmaf(bf_lo(hD), wD, acc0); acc1 = fmaf(bf_hi(hD), wD, acc1);
        }
        for (; j < deg; j++){
            uint oA = ssh[wv][j]+lane;
            float wA = wsh[wv][j][comp];
            uint hA = hb2[oA];
            acc0 = fmaf(bf_lo(hA), wA, acc0);
            acc1 = fmaf(bf_hi(hA), wA, acc1);
        }
    } else {
        float s0=0,s1=0,s2=0,s3=0;
        for (int j=lane; j<deg; j+=64){
            int s = bsrc[base+j];
            float4 av = as1v[s];
            float e0=cexp(lrelu(av.x+adv.x));
            float e1=cexp(lrelu(av.y+adv.y));
            float e2=cexp(lrelu(av.z+adv.z));
            float e3=cexp(lrelu(av.w+adv.w));
            s0+=e0; s1+=e1; s2+=e2; s3+=e3;
            *(float4*)&exb[(size_t)(base+j)*4] = make_float4(e0,e1,e2,e3);
        }
        #pragma unroll
        for (int d=32; d>=1; d>>=1){
            s0+=__shfl_xor(s0,d); s1+=__shfl_xor(s1,d);
            s2+=__shfl_xor(s2,d); s3+=__shfl_xor(s3,d);
        }
        float invc = 1.0f / sel4(s0,s1,s2,s3,comp);
        for (int j=0;j<deg;j++){
            int s = bsrc[base+j];
            float w = exb[(size_t)(base+j)*4 + comp]*invc;
            uint hv = hb2[((uint)s<<6)+lane];
            acc0 = fmaf(bf_lo(hv), w, acc0);
            acc1 = fmaf(bf_hi(hv), w, acc1);
        }
    }
    float2 bv = *(const float2*)&b1[2*lane];
    float r0 = acc0 + bv.x;
    float r1 = acc1 + bv.y;
    r0 = r0 > 0.f ? r0 : (__expf(r0) - 1.f);
    r1 = r1 > 0.f ? r1 : (__expf(r1) - 1.f);
    hb1[(size_t)wid*64 + lane] = f2bf(r0) | (f2bf(r1)<<16);
}

// ---------------- GEMM2 (h2 = bf16(h1) @ W2, bf16-packed out) + alpha2 ----------------
__global__ __launch_bounds__(512) void k_l2pre(const uint* __restrict__ hb1,
    const float* __restrict__ W2, const float* __restrict__ asrc2,
    const float* __restrict__ adst2, uint* __restrict__ h2b,
    float* __restrict__ as2, float* __restrict__ ad2, int N)
{
    __shared__ __align__(16) float w2s[4096];
    __shared__ float a2s[32], a2d[32];
    int tid = threadIdx.x;
    #pragma unroll
    for (int q=0;q<2;q++){
        int idx = q*2048 + tid*4;
        *(float4*)&w2s[idx] = *(const float4*)&W2[idx];
    }
    if (tid < 32){ a2s[tid] = asrc2[tid]; a2d[tid] = adst2[tid]; }
    __syncthreads();
    int node = blockIdx.x*16 + (tid>>5);
    if (node >= N) return;
    int c = tid & 31;
    float acc = 0.f;
    #pragma unroll
    for (int k=0;k<128;k+=8){
        uint4 u = *(const uint4*)&hb1[(size_t)node*64 + (k>>1)];
        acc = fmaf(bf_lo(u.x), w2s[(k+0)*32+c], acc);
        acc = fmaf(bf_hi(u.x), w2s[(k+1)*32+c], acc);
        acc = fmaf(bf_lo(u.y), w2s[(k+2)*32+c], acc);
        acc = fmaf(bf_hi(u.y), w2s[(k+3)*32+c], acc);
        acc = fmaf(bf_lo(u.z), w2s[(k+4)*32+c], acc);
        acc = fmaf(bf_hi(u.z), w2s[(k+5)*32+c], acc);
        acc = fmaf(bf_lo(u.w), w2s[(k+6)*32+c], acc);
        acc = fmaf(bf_hi(u.w), w2s[(k+7)*32+c], acc);
    }
    float pr = __shfl_xor(acc, 1);
    if ((c & 1) == 0)
        h2b[(size_t)node*16 + (c>>1)] = f2bf(acc) | (f2bf(pr)<<16);
    float ps = acc * a2s[c], pd = acc * a2d[c];
    #pragma unroll
    for (int d=16; d>=1; d>>=1){ ps += __shfl_xor(ps,d); pd += __shfl_xor(pd,d); }
    if (c == 0){ as2[node] = ps; ad2[node] = pd; }
}

// ---------------- layer-2 softmax (max-free) + aggregate + bias -> output ----------------
__global__ __launch_bounds__(512) void k_agg2(const uint* __restrict__ h2b,
    const float* __restrict__ as2, const float* __restrict__ ad2,
    const int* __restrict__ offs, const int* __restrict__ bsrc,
    const float* __restrict__ b2, float* __restrict__ exb,
    float* __restrict__ outp, int N)
{
    __shared__ float w2sh[8][64];
    __shared__ int   s2sh[8][64];     // src<<4
    int wv   = threadIdx.x >> 6;
    int wid  = (blockIdx.x << 3) + wv;
    int lane = threadIdx.x & 63;
    if (wid >= N) return;
    int base = offs[wid], deg = offs[wid+1] - base;
    float adn = ad2[wid];
    const int c2 = lane & 15, slot = lane >> 4;
    float acc0 = 0.f, acc1 = 0.f;

    if (deg <= 64){
        const bool act = lane < deg;
        int sreg = 0; float e = 0.f;
        if (act){ sreg = bsrc[base+lane]; e = cexp(lrelu(as2[sreg] + adn)); }
        float sum = e;
        #pragma unroll
        for (int d=32; d>=1; d>>=1) sum += __shfl_xor(sum,d);
        if (act){
            s2sh[wv][lane] = sreg << 4;
            w2sh[wv][lane] = e * __builtin_amdgcn_rcpf(sum);
        }
        int j = slot;
        for (; j+4 < deg; j += 8){
            uint oA = (uint)(s2sh[wv][j] + c2);
            uint oB = (uint)(s2sh[wv][j+4] + c2);
            float wA = w2sh[wv][j], wB = w2sh[wv][j+4];
            uint uA = h2b[oA], uB = h2b[oB];
            acc0 = fmaf(bf_lo(uA), wA, acc0); acc1 = fmaf(bf_hi(uA), wA, acc1);
            acc0 = fmaf(bf_lo(uB), wB, acc0); acc1 = fmaf(bf_hi(uB), wB, acc1);
        }
        for (; j < deg; j += 4){
            uint o  = (uint)(s2sh[wv][j] + c2);
            float w = w2sh[wv][j];
            uint u = h2b[o];
            acc0 = fmaf(bf_lo(u), w, acc0);
            acc1 = fmaf(bf_hi(u), w, acc1);
        }
    } else {
        float sum = 0.f;
        for (int j=lane; j<deg; j+=64){
            int s = bsrc[base+j];
            float ex = cexp(lrelu(as2[s] + adn));
            sum += ex;
            exb[base+j] = ex;
        }
        #pragma unroll
        for (int d=32; d>=1; d>>=1) sum += __shfl_xor(sum,d);
        float inv = 1.f/sum;
        for (int j=slot; j<deg; j+=4){
            int s  = bsrc[base+j];
            float w = exb[base+j]*inv;
            uint u = h2b[((uint)s<<4) + c2];
            acc0 = fmaf(bf_lo(u), w, acc0);
            acc1 = fmaf(bf_hi(u), w, acc1);
        }
    }
    acc0 += __shfl_xor(acc0, 16); acc0 += __shfl_xor(acc0, 32);
    acc1 += __shfl_xor(acc1, 16); acc1 += __shfl_xor(acc1, 32);
    if (lane < 16){
        float2 bv = *(const float2*)&b2[2*c2];
        *(float2*)&outp[(size_t)wid*32 + 2*c2] = make_float2(acc0 + bv.x, acc1 + bv.y);
    }
}

extern "C" void kernel_launch(void* const* d_in, const int* in_sizes, int n_in,
                              void* d_out, int out_size, void* d_ws, size_t ws_size,
                              hipStream_t stream)
{
    const float* x     = (const float*)d_in[0];
    const int*   ei    = (const int*)d_in[1];
    const float* W1    = (const float*)d_in[2];
    const float* at_s1 = (const float*)d_in[3];
    const float* at_d1 = (const float*)d_in[4];
    const float* b1    = (const float*)d_in[5];
    const float* W2    = (const float*)d_in[6];
    const float* at_s2 = (const float*)d_in[7];
    const float* at_d2 = (const float*)d_in[8];
    const float* b2    = (const float*)d_in[9];
    float* outp = (float*)d_out;

    const int N = in_sizes[0] / 128;
    const int E = in_sizes[1] / 2;
    const int Etot = E + N;

    const int NB = (N + 255) >> 8;             // dst buckets (dst>>8)
    const int NC = (Etot + 4095) / 4096;       // edge chunks
    const int T  = NB * NC;
    const int L1 = (T + 255) / 256;

    float* f = (float*)d_ws;
    size_t off = 0;
    uint*  hb2 = (uint*)(f + off); off += (size_t)N*64;   // bf16 h  [N][64]
    uint*  hb1 = (uint*)(f + off); off += (size_t)N*64;   // bf16 h1 [N][64]
    float* exb = f + off; off += (size_t)Etot*4;
    float* as1 = f + off; off += (size_t)N*4;
    float* ad1 = f + off; off += (size_t)N*4;
    uint*  h2b = (uint*)(f + off); off += (size_t)N*16;   // bf16 h2 [N][16]
    float* as2 = f + off; off += (size_t)N;
    float* ad2 = f + off; off += (size_t)N;
    ushort* wtb = (ushort*)(f + off); off += 8192;        // W1^T bf16 (32KB)
    int* ib       = (int*)(f + off);
    int* offs     = ib;                        // N+1 (+pad)
    int* bh       = ib + N + 8;                // T
    int* bhs      = bh + T;                    // T
    int* partials2= bhs + T;                   // 256
    uint* epack   = (uint*)(partials2 + 256);  // Etot
    int* bsrc     = (int*)(epack + Etot);      // Etot

    const int GB = (N+63)/64;
    const int AB = (N+3)/4;

    k_prep <<<16, 256, 0, stream>>>(W1, wtb, offs, N, Etot);
    k_g1b  <<<GB+NC, 512, 0, stream>>>(x, wtb, hb2, N, GB, ei, bh, E, Etot, NC, NB);
    k_a1sc <<<AB+L1, 256, 0, stream>>>(hb2, at_s1, at_d1, as1, ad1, N, AB,
                                       bh, bhs, partials2, T);
    if (L1 <= 256){
        k_bscat<<<NC, 256, 0, stream>>>(ei, bhs, partials2, L1, epack, E, Etot, NC, NB);
        k_bfin <<<NB, 256, 0, stream>>>(epack, bhs, partials2, L1, bsrc, offs, N, NB, NC, Etot);
    } else {
        k_bscan2s<<<1, 1, 0, stream>>>(bhs, bh, T);
        k_bscat<<<NC, 256, 0, stream>>>(ei, bhs, partials2, 0, epack, E, Etot, NC, NB);
        k_bfin <<<NB, 256, 0, stream>>>(epack, bhs, partials2, 0, bsrc, offs, N, NB, NC, Etot);
    }
    k_agg1 <<<(N+7)/8, 512, 0, stream>>>(hb2, (const float4*)as1, (const float4*)ad1,
                                         offs, bsrc, b1, exb, hb1, N);
    k_l2pre<<<(N+15)/16, 512, 0, stream>>>(hb1, W2, at_s2, at_d2, h2b, as2, ad2, N);
    k_agg2 <<<(N+7)/8, 512, 0, stream>>>(h2b, as2, ad2, offs, bsrc, b2, exb, outp, N);
}

// Round 13
// 146.160 us; speedup vs baseline: 1.0033x; 1.0033x over previous
//
#include <hip/hip_runtime.h>
#include <math.h>

#define NEG_SLOPE 0.2f
typedef unsigned int uint;
typedef __attribute__((ext_vector_type(8))) short short8;
typedef __attribute__((ext_vector_type(4))) float floatx4;

__device__ __forceinline__ float lrelu(float x){ return x > 0.f ? x : NEG_SLOPE*x; }
__device__ __forceinline__ float sel4(float a,float b,float c,float d,int comp){
    return comp==0 ? a : (comp==1 ? b : (comp==2 ? c : d));
}
__device__ __forceinline__ uint f2bf(float f){
    uint u = __float_as_uint(f);
    return (u + 0x7FFFu + ((u>>16)&1u)) >> 16;
}
__device__ __forceinline__ float bf_lo(uint u){ return __uint_as_float(u<<16); }
__device__ __forceinline__ float bf_hi(uint u){ return __uint_as_float(u & 0xFFFF0000u); }
__device__ __forceinline__ float cexp(float x){ return __expf(fminf(x, 60.f)); }

// ---------------- prep: W1^T -> bf16 (16 blocks) + offs[N]=Etot ----------------
__global__ __launch_bounds__(256) void k_prep(const float* __restrict__ W,
                                              ushort* __restrict__ wtb,
                                              int* __restrict__ offs, int N, int Etot)
{
    if (blockIdx.x == 0 && threadIdx.x == 0) offs[N] = Etot;
    int flat = blockIdx.x*1024 + threadIdx.x*4;
    int k = flat >> 7, c = flat & 127;
    float4 wv = *(const float4*)&W[flat];
    wtb[(size_t)(c+0)*128 + k] = (ushort)f2bf(wv.x);
    wtb[(size_t)(c+1)*128 + k] = (ushort)f2bf(wv.y);
    wtb[(size_t)(c+2)*128 + k] = (ushort)f2bf(wv.z);
    wtb[(size_t)(c+3)*128 + k] = (ushort)f2bf(wv.w);
}

// ---------------- MERGED: MFMA GEMM1 (blocks < GB, 8 waves) + bucket histogram ----------------
// B-fragments prefetched from global wtb BEFORE the barrier (overlap staging latency).
__global__ __launch_bounds__(512) void k_g1b(const float* __restrict__ x,
    const ushort* __restrict__ wtb, uint* __restrict__ hb2, int N, int GB,
    const int* __restrict__ ei, int* __restrict__ bh, int E, int Etot, int NC, int NB)
{
    if (blockIdx.x >= GB){
        __shared__ uint hist[256];
        int c = blockIdx.x - GB;
        if (threadIdx.x < 256) hist[threadIdx.x] = 0;
        __syncthreads();
        int e0 = c*4096;
        #pragma unroll
        for (int r=0;r<8;r++){
            int e = e0 + r*512 + threadIdx.x;
            if (e < Etot){
                int d = (e < E) ? ei[E+e] : (e-E);
                atomicAdd(&hist[d>>8], 1u);
            }
        }
        __syncthreads();
        int b = threadIdx.x;
        if (b < NB) bh[(size_t)b*NC + c] = (int)hist[b];
        return;
    }
    __shared__ __align__(16) ushort xt[64][136];
    const int tid = threadIdx.x;
    const int row0 = blockIdx.x * 64;
    const int wv_ = tid >> 6, lane = tid & 63;
    const int l15 = lane & 15, hi = lane >> 4;
    const int rw = wv_ & 3, ch = wv_ >> 2;
    const int arow = rw*16 + l15;
    #pragma unroll
    for (int j=0;j<4;j++){
        int flat = j*2048 + tid*4;
        int r = flat >> 7, c = flat & 127;
        int gr = row0 + r;
        float4 xv = (gr < N) ? *(const float4*)&x[(size_t)gr*128 + c]
                             : make_float4(0.f,0.f,0.f,0.f);
        uint2 p;
        p.x = f2bf(xv.x) | (f2bf(xv.y)<<16);
        p.y = f2bf(xv.z) | (f2bf(xv.w)<<16);
        *(uint2*)&xt[r][c] = p;
    }
    // prefetch all 16 B-fragments (independent of LDS) so they fly during staging+barrier
    short8 bfrag[4][4];
    #pragma unroll
    for (int ks=0; ks<4; ks++)
        #pragma unroll
        for (int c4=0; c4<4; c4++)
            bfrag[ks][c4] = *(const short8*)&wtb[(size_t)((ch*4+c4)*16 + l15)*128 + ks*32 + hi*8];
    __syncthreads();
    floatx4 acc[4];
    #pragma unroll
    for (int t=0;t<4;t++) acc[t] = (floatx4){0.f,0.f,0.f,0.f};
    #pragma unroll
    for (int ks=0; ks<4; ks++){
        short8 a = *(short8*)&xt[arow][ks*32 + hi*8];
        #pragma unroll
        for (int c4=0; c4<4; c4++)
            acc[c4] = __builtin_amdgcn_mfma_f32_16x16x32_bf16(a, bfrag[ks][c4], acc[c4], 0, 0, 0);
    }
    #pragma unroll
    for (int c4=0; c4<4; c4++){
        int ct = ch*4 + c4;
        #pragma unroll
        for (int r=0;r<4;r++){
            float v  = acc[c4][r];
            float pr = __shfl_xor(v, 1);
            int gr = row0 + rw*16 + (hi<<2) + r;
            if (((lane & 1) == 0) && gr < N)
                hb2[(size_t)gr*64 + ct*8 + (l15>>1)] = f2bf(v) | (f2bf(pr)<<16);
        }
    }
}

// ---------------- MERGED: alpha1 (blocks < AB) + bucket-scan level1 ----------------
__global__ __launch_bounds__(256) void k_a1sc(const uint* __restrict__ hb2,
        const float* __restrict__ at_s, const float* __restrict__ at_d,
        float* __restrict__ as1, float* __restrict__ ad1, int N, int AB,
        const int* __restrict__ bh, int* __restrict__ bhs, int* __restrict__ partials2, int T)
{
    __shared__ int sm[256];
    if (blockIdx.x >= AB){
        int bid = blockIdx.x - AB;
        int tid = threadIdx.x;
        int i = bid*256 + tid;
        int v = (i < T) ? bh[i] : 0;
        sm[tid] = v;
        __syncthreads();
        for (int d=1; d<256; d<<=1){
            int t = (tid >= d) ? sm[tid-d] : 0;
            __syncthreads();
            sm[tid] += t;
            __syncthreads();
        }
        if (i < T) bhs[i] = sm[tid] - v;
        if (tid == 255) partials2[bid] = sm[255];
        return;
    }
    int wid = (blockIdx.x << 2) + (threadIdx.x >> 6);
    int lane = threadIdx.x & 63;
    if (wid >= N) return;
    uint hv = hb2[(size_t)wid*64 + lane];
    float f0 = bf_lo(hv), f1 = bf_hi(hv);
    float2 asv = *(const float2*)&at_s[2*lane];
    float2 adv = *(const float2*)&at_d[2*lane];
    float sa = f0*asv.x + f1*asv.y;
    float da = f0*adv.x + f1*adv.y;
    #pragma unroll
    for (int d=8; d>=1; d>>=1){ sa += __shfl_xor(sa,d); da += __shfl_xor(da,d); }
    if ((lane & 15) == 0){
        int head = lane >> 4;
        as1[(size_t)wid*4 + head] = sa;
        ad1[(size_t)wid*4 + head] = da;
    }
}

// serial level-2 fallback (only if L1 > 256; produces FINAL bhs)
__global__ void k_bscan2s(int* __restrict__ bhs, const int* __restrict__ bh, int T){
    if (threadIdx.x == 0){
        int run = 0;
        for (int i=0;i<T;i++){ bhs[i] = run; run += bh[i]; }
    }
}

// ---------------- scatter edges to bucket-major order (inline level-2 scan) ----------------
__global__ __launch_bounds__(256) void k_bscat(const int* __restrict__ ei,
        const int* __restrict__ bhs, const int* __restrict__ partials2, int L1e,
        uint* __restrict__ epack, int E, int Etot, int NC, int NB)
{
    __shared__ int sm[256];
    __shared__ int pbase[256];
    __shared__ uint cnt[256];
    int c = blockIdx.x, tid = threadIdx.x;
    int v = (tid < L1e) ? partials2[tid] : 0;
    sm[tid] = v;
    __syncthreads();
    for (int d=1; d<256; d<<=1){
        int t = (tid >= d) ? sm[tid-d] : 0;
        __syncthreads();
        sm[tid] += t;
        __syncthreads();
    }
    if (tid < NB){
        int i = tid*NC + c;
        int boff = (L1e == 0 || (i>>8) == 0) ? 0 : sm[(i>>8)-1];
        pbase[tid] = bhs[i] + boff;
    }
    cnt[tid] = 0;
    __syncthreads();
    int e0 = c*4096;
    #pragma unroll
    for (int r=0;r<16;r++){
        int e = e0 + r*256 + tid;
        if (e < Etot){
            int d, s;
            if (e < E){ s = ei[e]; d = ei[E+e]; }
            else      { s = e - E; d = e - E; }
            int b = d >> 8;
            uint lr = atomicAdd(&cnt[b], 1u);
            epack[pbase[b] + (int)lr] = (uint)s | ((uint)(d & 255) << 16);
        }
    }
}

// ---------------- finalize: per-bucket node offsets + bsrc (ushort) ----------------
__global__ __launch_bounds__(256) void k_bfin(const uint* __restrict__ epack,
        const int* __restrict__ bhs, const int* __restrict__ partials2, int L1e,
        ushort* __restrict__ bsrc, int* __restrict__ offs, int N, int NB, int NC, int Etot)
{
    __shared__ int sm[256];
    __shared__ int cnt[256], lofs[256], cnt2[256];
    int b = blockIdx.x, tid = threadIdx.x;
    int v = (tid < L1e) ? partials2[tid] : 0;
    sm[tid] = v;
    __syncthreads();
    for (int d=1; d<256; d<<=1){
        int t = (tid >= d) ? sm[tid-d] : 0;
        __syncthreads();
        sm[tid] += t;
        __syncthreads();
    }
    int i0 = b*NC;
    int start = bhs[i0] + ((L1e==0 || (i0>>8)==0) ? 0 : sm[(i0>>8)-1]);
    int end;
    if (b+1 < NB){
        int i1 = (b+1)*NC;
        end = bhs[i1] + ((L1e==0 || (i1>>8)==0) ? 0 : sm[(i1>>8)-1]);
    } else end = Etot;
    __syncthreads();
    cnt[tid] = 0; cnt2[tid] = 0;
    __syncthreads();
    for (int e = start + tid; e < end; e += 256)
        atomicAdd((uint*)&cnt[(epack[e] >> 16) & 255], 1u);
    __syncthreads();
    int v2 = cnt[tid];
    sm[tid] = v2;
    __syncthreads();
    for (int d=1; d<256; d<<=1){
        int t = (tid >= d) ? sm[tid-d] : 0;
        __syncthreads();
        sm[tid] += t;
        __syncthreads();
    }
    lofs[tid] = sm[tid] - v2;
    int nd = b*256 + tid;
    if (nd <= N) offs[nd] = start + sm[tid] - v2;
    __syncthreads();
    for (int e = start + tid; e < end; e += 256){
        uint u = epack[e];
        int dl = (u >> 16) & 255;
        int r = (int)atomicAdd((uint*)&cnt2[dl], 1u);
        bsrc[start + lofs[dl] + r] = (ushort)(u & 0xFFFFu);
    }
}

// ---------------- layer-1 softmax (max-free) + aggregate + bias + ELU -> bf16 h1 ----------------
__global__ __launch_bounds__(512) void k_agg1(const uint* __restrict__ hb2,
    const float4* __restrict__ as1v, const float4* __restrict__ ad1v,
    const int* __restrict__ offs, const ushort* __restrict__ bsrc,
    const float* __restrict__ b1, float* __restrict__ exb,
    uint* __restrict__ hb1, int N)
{
    __shared__ float wsh[8][64][4];   // [wave][edge][head]
    __shared__ int   ssh[8][64];      // [wave][edge] src<<6
    int wv   = threadIdx.x >> 6;
    int wid  = (blockIdx.x << 3) + wv;
    int lane = threadIdx.x & 63;
    if (wid >= N) return;
    int base = offs[wid];
    int deg  = offs[wid+1] - base;
    float4 adv = ad1v[wid];
    const int comp = lane >> 4;
    float acc0=0.f, acc1=0.f;

    if (deg <= 64){
        const bool act = lane < deg;
        int sreg = 0;
        float e0=0.f,e1=0.f,e2=0.f,e3=0.f;
        if (act){
            sreg = (int)bsrc[base+lane];
            float4 av = as1v[sreg];
            e0=cexp(lrelu(av.x+adv.x)); e1=cexp(lrelu(av.y+adv.y));
            e2=cexp(lrelu(av.z+adv.z)); e3=cexp(lrelu(av.w+adv.w));
        }
        float s0=e0,s1=e1,s2=e2,s3=e3;
        #pragma unroll
        for (int d=32; d>=1; d>>=1){
            s0+=__shfl_xor(s0,d); s1+=__shfl_xor(s1,d);
            s2+=__shfl_xor(s2,d); s3+=__shfl_xor(s3,d);
        }
        if (act){
            float i0=__builtin_amdgcn_rcpf(s0), i1=__builtin_amdgcn_rcpf(s1);
            float i2=__builtin_amdgcn_rcpf(s2), i3=__builtin_amdgcn_rcpf(s3);
            ssh[wv][lane]    = sreg << 6;
            wsh[wv][lane][0] = e0*i0;
            wsh[wv][lane][1] = e1*i1;
            wsh[wv][lane][2] = e2*i2;
            wsh[wv][lane][3] = e3*i3;
        }
        int j=0;
        for (; j+15 < deg; j+=16){
            uint o[16], h[16]; float w[16];
            #pragma unroll
            for (int q=0;q<16;q++) o[q] = (uint)ssh[wv][j+q] + lane;
            #pragma unroll
            for (int q=0;q<16;q++){ h[q] = hb2[o[q]]; w[q] = wsh[wv][j+q][comp]; }
            #pragma unroll
            for (int q=0;q<16;q++){
                acc0 = fmaf(bf_lo(h[q]), w[q], acc0);
                acc1 = fmaf(bf_hi(h[q]), w[q], acc1);
            }
        }
        for (; j+7 < deg; j+=8){
            uint o[8], h[8]; float w[8];
            #pragma unroll
            for (int q=0;q<8;q++) o[q] = (uint)ssh[wv][j+q] + lane;
            #pragma unroll
            for (int q=0;q<8;q++){ h[q] = hb2[o[q]]; w[q] = wsh[wv][j+q][comp]; }
            #pragma unroll
            for (int q=0;q<8;q++){
                acc0 = fmaf(bf_lo(h[q]), w[q], acc0);
                acc1 = fmaf(bf_hi(h[q]), w[q], acc1);
            }
        }
        for (; j+3 < deg; j+=4){
            uint o[4], h[4]; float w[4];
            #pragma unroll
            for (int q=0;q<4;q++) o[q] = (uint)ssh[wv][j+q] + lane;
            #pragma unroll
            for (int q=0;q<4;q++){ h[q] = hb2[o[q]]; w[q] = wsh[wv][j+q][comp]; }
            #pragma unroll
            for (int q=0;q<4;q++){
                acc0 = fmaf(bf_lo(h[q]), w[q], acc0);
                acc1 = fmaf(bf_hi(h[q]), w[q], acc1);
            }
        }
        for (; j < deg; j++){
            uint oA = (uint)ssh[wv][j] + lane;
            float wA = wsh[wv][j][comp];
            uint hA = hb2[oA];
            acc0 = fmaf(bf_lo(hA), wA, acc0);
            acc1 = fmaf(bf_hi(hA), wA, acc1);
        }
    } else {
        float s0=0,s1=0,s2=0,s3=0;
        for (int j=lane; j<deg; j+=64){
            int s = (int)bsrc[base+j];
            float4 av = as1v[s];
            float e0=cexp(lrelu(av.x+adv.x));
            float e1=cexp(lrelu(av.y+adv.y));
            float e2=cexp(lrelu(av.z+adv.z));
            float e3=cexp(lrelu(av.w+adv.w));
            s0+=e0; s1+=e1; s2+=e2; s3+=e3;
            *(float4*)&exb[(size_t)(base+j)*4] = make_float4(e0,e1,e2,e3);
        }
        #pragma unroll
        for (int d=32; d>=1; d>>=1){
            s0+=__shfl_xor(s0,d); s1+=__shfl_xor(s1,d);
            s2+=__shfl_xor(s2,d); s3+=__shfl_xor(s3,d);
        }
        float invc = 1.0f / sel4(s0,s1,s2,s3,comp);
        for (int j=0;j<deg;j++){
            int s = (int)bsrc[base+j];
            float w = exb[(size_t)(base+j)*4 + comp]*invc;
            uint hv = hb2[((uint)s<<6)+lane];
            acc0 = fmaf(bf_lo(hv), w, acc0);
            acc1 = fmaf(bf_hi(hv), w, acc1);
        }
    }
    float2 bv = *(const float2*)&b1[2*lane];
    float r0 = acc0 + bv.x;
    float r1 = acc1 + bv.y;
    r0 = r0 > 0.f ? r0 : (__expf(r0) - 1.f);
    r1 = r1 > 0.f ? r1 : (__expf(r1) - 1.f);
    hb1[(size_t)wid*64 + lane] = f2bf(r0) | (f2bf(r1)<<16);
}

// ---------------- GEMM2 (h2 = bf16(h1) @ W2, bf16-packed out) + alpha2 ----------------
__global__ __launch_bounds__(512) void k_l2pre(const uint* __restrict__ hb1,
    const float* __restrict__ W2, const float* __restrict__ asrc2,
    const float* __restrict__ adst2, uint* __restrict__ h2b,
    float* __restrict__ as2, float* __restrict__ ad2, int N)
{
    __shared__ __align__(16) float w2s[4096];
    __shared__ float a2s[32], a2d[32];
    int tid = threadIdx.x;
    #pragma unroll
    for (int q=0;q<2;q++){
        int idx = q*2048 + tid*4;
        *(float4*)&w2s[idx] = *(const float4*)&W2[idx];
    }
    if (tid < 32){ a2s[tid] = asrc2[tid]; a2d[tid] = adst2[tid]; }
    __syncthreads();
    int node = blockIdx.x*16 + (tid>>5);
    if (node >= N) return;
    int c = tid & 31;
    float acc = 0.f;
    #pragma unroll
    for (int k=0;k<128;k+=8){
        uint4 u = *(const uint4*)&hb1[(size_t)node*64 + (k>>1)];
        acc = fmaf(bf_lo(u.x), w2s[(k+0)*32+c], acc);
        acc = fmaf(bf_hi(u.x), w2s[(k+1)*32+c], acc);
        acc = fmaf(bf_lo(u.y), w2s[(k+2)*32+c], acc);
        acc = fmaf(bf_hi(u.y), w2s[(k+3)*32+c], acc);
        acc = fmaf(bf_lo(u.z), w2s[(k+4)*32+c], acc);
        acc = fmaf(bf_hi(u.z), w2s[(k+5)*32+c], acc);
        acc = fmaf(bf_lo(u.w), w2s[(k+6)*32+c], acc);
        acc = fmaf(bf_hi(u.w), w2s[(k+7)*32+c], acc);
    }
    float pr = __shfl_xor(acc, 1);
    if ((c & 1) == 0)
        h2b[(size_t)node*16 + (c>>1)] = f2bf(acc) | (f2bf(pr)<<16);
    float ps = acc * a2s[c], pd = acc * a2d[c];
    #pragma unroll
    for (int d=16; d>=1; d>>=1){ ps += __shfl_xor(ps,d); pd += __shfl_xor(pd,d); }
    if (c == 0){ as2[node] = ps; ad2[node] = pd; }
}

// ---------------- layer-2 softmax (max-free) + aggregate + bias -> output ----------------
__global__ __launch_bounds__(512) void k_agg2(const uint* __restrict__ h2b,
    const float* __restrict__ as2, const float* __restrict__ ad2,
    const int* __restrict__ offs, const ushort* __restrict__ bsrc,
    const float* __restrict__ b2, float* __restrict__ exb,
    float* __restrict__ outp, int N)
{
    __shared__ float w2sh[8][64];
    __shared__ int   s2sh[8][64];     // src<<4
    int wv   = threadIdx.x >> 6;
    int wid  = (blockIdx.x << 3) + wv;
    int lane = threadIdx.x & 63;
    if (wid >= N) return;
    int base = offs[wid], deg = offs[wid+1] - base;
    float adn = ad2[wid];
    const int c2 = lane & 15, slot = lane >> 4;
    float acc0 = 0.f, acc1 = 0.f;

    if (deg <= 64){
        const bool act = lane < deg;
        int sreg = 0; float e = 0.f;
        if (act){ sreg = (int)bsrc[base+lane]; e = cexp(lrelu(as2[sreg] + adn)); }
        float sum = e;
        #pragma unroll
        for (int d=32; d>=1; d>>=1) sum += __shfl_xor(sum,d);
        if (act){
            s2sh[wv][lane] = sreg << 4;
            w2sh[wv][lane] = e * __builtin_amdgcn_rcpf(sum);
        }
        int j = slot;
        for (; j+4 < deg; j += 8){
            uint oA = (uint)(s2sh[wv][j] + c2);
            uint oB = (uint)(s2sh[wv][j+4] + c2);
            float wA = w2sh[wv][j], wB = w2sh[wv][j+4];
            uint uA = h2b[oA], uB = h2b[oB];
            acc0 = fmaf(bf_lo(uA), wA, acc0); acc1 = fmaf(bf_hi(uA), wA, acc1);
            acc0 = fmaf(bf_lo(uB), wB, acc0); acc1 = fmaf(bf_hi(uB), wB, acc1);
        }
        for (; j < deg; j += 4){
            uint o  = (uint)(s2sh[wv][j] + c2);
            float w = w2sh[wv][j];
            uint u = h2b[o];
            acc0 = fmaf(bf_lo(u), w, acc0);
            acc1 = fmaf(bf_hi(u), w, acc1);
        }
    } else {
        float sum = 0.f;
        for (int j=lane; j<deg; j+=64){
            int s = (int)bsrc[base+j];
            float ex = cexp(lrelu(as2[s] + adn));
            sum += ex;
            exb[base+j] = ex;
        }
        #pragma unroll
        for (int d=32; d>=1; d>>=1) sum += __shfl_xor(sum,d);
        float inv = 1.f/sum;
        for (int j=slot; j<deg; j+=4){
            int s  = (int)bsrc[base+j];
            float w = exb[base+j]*inv;
            uint u = h2b[((uint)s<<4) + c2];
            acc0 = fmaf(bf_lo(u), w, acc0);
            acc1 = fmaf(bf_hi(u), w, acc1);
        }
    }
    acc0 += __shfl_xor(acc0, 16); acc0 += __shfl_xor(acc0, 32);
    acc1 += __shfl_xor(acc1, 16); acc1 += __shfl_xor(acc1, 32);
    if (lane < 16){
        float2 bv = *(const float2*)&b2[2*c2];
        *(float2*)&outp[(size_t)wid*32 + 2*c2] = make_float2(acc0 + bv.x, acc1 + bv.y);
    }
}

extern "C" void kernel_launch(void* const* d_in, const int* in_sizes, int n_in,
                              void* d_out, int out_size, void* d_ws, size_t ws_size,
                              hipStream_t stream)
{
    const float* x     = (const float*)d_in[0];
    const int*   ei    = (const int*)d_in[1];
    const float* W1    = (const float*)d_in[2];
    const float* at_s1 = (const float*)d_in[3];
    const float* at_d1 = (const float*)d_in[4];
    const float* b1    = (const float*)d_in[5];
    const float* W2    = (const float*)d_in[6];
    const float* at_s2 = (const float*)d_in[7];
    const float* at_d2 = (const float*)d_in[8];
    const float* b2    = (const float*)d_in[9];
    float* outp = (float*)d_out;

    const int N = in_sizes[0] / 128;
    const int E = in_sizes[1] / 2;
    const int Etot = E + N;

    const int NB = (N + 255) >> 8;             // dst buckets (dst>>8)
    const int NC = (Etot + 4095) / 4096;       // edge chunks
    const int T  = NB * NC;
    const int L1 = (T + 255) / 256;

    float* f = (float*)d_ws;
    size_t off = 0;
    uint*  hb2 = (uint*)(f + off); off += (size_t)N*64;   // bf16 h  [N][64]
    uint*  hb1 = (uint*)(f + off); off += (size_t)N*64;   // bf16 h1 [N][64]
    float* exb = f + off; off += (size_t)Etot*4;
    float* as1 = f + off; off += (size_t)N*4;
    float* ad1 = f + off; off += (size_t)N*4;
    uint*  h2b = (uint*)(f + off); off += (size_t)N*16;   // bf16 h2 [N][16]
    float* as2 = f + off; off += (size_t)N;
    float* ad2 = f + off; off += (size_t)N;
    ushort* wtb = (ushort*)(f + off); off += 8192;        // W1^T bf16 (32KB)
    int* ib       = (int*)(f + off);
    int* offs     = ib;                        // N+1 (+pad)
    int* bh       = ib + N + 8;                // T
    int* bhs      = bh + T;                    // T
    int* partials2= bhs + T;                   // 256
    uint* epack   = (uint*)(partials2 + 256);  // Etot
    ushort* bsrc  = (ushort*)(epack + Etot);   // Etot (ushort)

    const int GB = (N+63)/64;
    const int AB = (N+3)/4;

    k_prep <<<16, 256, 0, stream>>>(W1, wtb, offs, N, Etot);
    k_g1b  <<<GB+NC, 512, 0, stream>>>(x, wtb, hb2, N, GB, ei, bh, E, Etot, NC, NB);
    k_a1sc <<<AB+L1, 256, 0, stream>>>(hb2, at_s1, at_d1, as1, ad1, N, AB,
                                       bh, bhs, partials2, T);
    if (L1 <= 256){
        k_bscat<<<NC, 256, 0, stream>>>(ei, bhs, partials2, L1, epack, E, Etot, NC, NB);
        k_bfin <<<NB, 256, 0, stream>>>(epack, bhs, partials2, L1, bsrc, offs, N, NB, NC, Etot);
    } else {
        k_bscan2s<<<1, 1, 0, stream>>>(bhs, bh, T);
        k_bscat<<<NC, 256, 0, stream>>>(ei, bhs, partials2, 0, epack, E, Etot, NC, NB);
        k_bfin <<<NB, 256, 0, stream>>>(epack, bhs, partials2, 0, bsrc, offs, N, NB, NC, Etot);
    }
    k_agg1 <<<(N+7)/8, 512, 0, stream>>>(hb2, (const float4*)as1, (const float4*)ad1,
                                         offs, bsrc, b1, exb, hb1, N);
    k_l2pre<<<(N+15)/16, 512, 0, stream>>>(hb1, W2, at_s2, at_d2, h2b, as2, ad2, N);
    k_agg2 <<<(N+7)/8, 512, 0, stream>>>(h2b, as2, ad2, offs, bsrc, b2, exb, outp, N);
}